// Round 5
// baseline (160.683 us; speedup 1.0000x reference)
//
#include <hip/hip_runtime.h>
#include <hip/hip_bf16.h>

typedef __attribute__((ext_vector_type(8))) short bf16x8;
typedef __attribute__((ext_vector_type(4))) short s16x4;
typedef __attribute__((ext_vector_type(4))) float f32x4;

__device__ __forceinline__ short f2bf(float f) {
    union { float f; unsigned u; } v; v.f = f;
    unsigned r = v.u + 0x7fffu + ((v.u >> 16) & 1u);
    return (short)(r >> 16);
}

#define KP  800   // w1t K padded 784 -> 800 (25 * 32)
#define LDA 808   // A LDS row stride (784 + pad; 808*2B stride -> uniform banks for b128)
#define LDH 264   // h1 row stride

// ---------------- init: transpose/convert weights, pointer tables ----------------
__global__ void init_kernel(const float* __restrict__ W1, const float* __restrict__ W2,
                            const float* __restrict__ Wp, const float* __restrict__ bp,
                            const float* __restrict__ Wr1, const float* __restrict__ br1,
                            const float* __restrict__ Wr2, const float* __restrict__ br2,
                            short* __restrict__ w1t, short* __restrict__ w2t,
                            float* __restrict__ ptabs)
{
    int tid = blockIdx.x * blockDim.x + threadIdx.x;
    int stride = gridDim.x * blockDim.x;
    for (int i = tid; i < 784 * 256; i += stride) {      // coalesced W1 read, scattered 2B store
        int k = i >> 8, n = i & 255;
        w1t[n * KP + k] = f2bf(W1[i]);
    }
    for (int i = tid; i < 256 * 16; i += stride) {       // zero-pad k in [784,800)
        int n = i >> 4, k = 784 + (i & 15);
        w1t[n * KP + k] = 0;
    }
    for (int i = tid; i < 16 * 256; i += stride) {       // w2t[n][k] = W2[k][n], N padded to 16
        int n = i >> 8, k = i & 255;
        float v = (n < 10) ? W2[k * 10 + n] : 0.f;
        w2t[i] = f2bf(v);
    }
    if (blockIdx.x == 0 && threadIdx.x < 8) {            // pointer tables: 4 programs only
        int which = threadIdx.x >> 2, p = threadIdx.x & 3;
        const float* Wr = which ? Wr2 : Wr1;
        const float* br = which ? br2 : br1;
        float s[4];
        for (int q = 0; q < 4; q++) {
            float a = br[q];
            for (int j = 0; j < 16; j++) a += (Wp[p * 16 + j] + bp[j]) * Wr[j * 4 + q];
            s[q] = a;
        }
        float m = fmaxf(fmaxf(s[0], s[1]), fmaxf(s[2], s[3]));
        float e[4]; float tot = 0.f;
        for (int q = 0; q < 4; q++) { e[q] = __expf(s[q] - m); tot += e[q]; }
        for (int q = 0; q < 4; q++) ptabs[which * 16 + p * 4 + q] = e[q] / tot;
    }
}

// ---------------- fused main kernel ----------------
// 256 persistent blocks x 512 threads (8 waves). Block owns 256 consecutive rows
// = 8 chunks x 32 rows. A chunk = 100 KB CONTIGUOUS global read (whole rows),
// fp32->bf16, double-buffered in LDS. B-frags read from L2 straight into regs
// (no LDS, no barriers in the K-loop). Wave w owns output cols [32w, 32w+32).
__global__ __launch_bounds__(512, 2) void fused_kernel(
    const float* __restrict__ g_in, const float* __restrict__ onehot,
    const float* __restrict__ b1g, const float* __restrict__ b2g,
    const short* __restrict__ w1t, const short* __restrict__ w2t,
    const float* __restrict__ ptabs, float* __restrict__ out)
{
    __shared__ __align__(16) char lds[122496];
    short* Abuf  = (short*)lds;                 // [2][32][808] bf16 = 103,424 B
    short* h1    = (short*)(lds + 103424);      // [32][264] bf16   = 16,896 B
    float* probs = (float*)(lds + 120320);      // [32][10] f32     = 1,280 B
    float* dist1 = (float*)(lds + 121600);      // [8][10] f32      = 320 B
    float* dist2 = (float*)(lds + 121920);      // [8][10] f32      = 320 B
    int*   pids  = (int*)(lds + 122240);        // [64] int         = 256 B

    const int t = threadIdx.x;
    const int lane = t & 63, wave = t >> 6;
    const int l16 = lane & 15, lg = lane >> 4;
    const int blk = blockIdx.x;
    const float* gblock = g_in + (long)blk * 256 * 784;

    // ---- prologue: pids, zero A pad cols, stage chunk 0 ----
    if (t < 64) {
        const float* oh = onehot + ((long)blk * 64 + t) * 4;
        pids[t] = (int)(oh[1] + 2.f * oh[2] + 3.f * oh[3] + 0.5f);
    }
    for (int i = t; i < 2 * 32 * 24; i += 512) {
        int b = i / 768, rem = i - b * 768;
        int rr = rem / 24, cc = rem - rr * 24;
        Abuf[b * 32 * LDA + rr * LDA + 784 + cc] = 0;
    }
    #pragma unroll
    for (int r = 0; r < 13; ++r) {
        if (r < 12 || t < 128) {
            int f = r * 2048 + t * 4;
            f32x4 x = *(const f32x4*)(gblock + f);
            int row = f / 784, col = f - row * 784;
            s16x4 a4;
            a4[0] = f2bf(x[0]); a4[1] = f2bf(x[1]); a4[2] = f2bf(x[2]); a4[3] = f2bf(x[3]);
            *(s16x4*)(Abuf + row * LDA + col) = a4;
        }
    }
    __syncthreads();

    // wave-constant bases
    const short* gw1 = w1t + (wave * 32 + l16) * KP + lg * 8;   // + ni*16*KP + s*32
    const float b1v0 = b1g[wave * 32 + l16];
    const float b1v1 = b1g[wave * 32 + 16 + l16];
    const float b2v = (l16 < 10) ? b2g[l16] : 0.f;

    // A staging helpers (macros so everything folds under unroll)
    #define A_ISSUE(r, xreg) { \
        if ((r) < 12 || t < 128) { \
            int f_ = (r) * 2048 + t * 4; \
            xreg = *(const f32x4*)(gnext + f_); \
        } }
    #define A_WRITE(r, xreg) { \
        if ((r) < 12 || t < 128) { \
            int f_ = (r) * 2048 + t * 4; \
            int row_ = f_ / 784, col_ = f_ - row_ * 784; \
            s16x4 a4_; \
            a4_[0] = f2bf(xreg[0]); a4_[1] = f2bf(xreg[1]); \
            a4_[2] = f2bf(xreg[2]); a4_[3] = f2bf(xreg[3]); \
            *(s16x4*)(Awr + row_ * LDA + col_) = a4_; \
        } }
    #define BF_ISSUE(s1, dst) { \
        dst[0] = *(const bf16x8*)(gw1 + (s1) * 32); \
        dst[1] = *(const bf16x8*)(gw1 + 16 * KP + (s1) * 32); }
    #define AF_ISSUE(s1, dst) { \
        dst[0] = *(const bf16x8*)(Ard + l16 * LDA + (s1) * 32 + lg * 8); \
        dst[1] = *(const bf16x8*)(Ard + (16 + l16) * LDA + (s1) * 32 + lg * 8); }
    #define DO_MFMA(af, bf) { \
        acc00 = __builtin_amdgcn_mfma_f32_16x16x32_bf16(af[0], bf[0], acc00, 0, 0, 0); \
        acc01 = __builtin_amdgcn_mfma_f32_16x16x32_bf16(af[0], bf[1], acc01, 0, 0, 0); \
        acc10 = __builtin_amdgcn_mfma_f32_16x16x32_bf16(af[1], bf[0], acc10, 0, 0, 0); \
        acc11 = __builtin_amdgcn_mfma_f32_16x16x32_bf16(af[1], bf[1], acc11, 0, 0, 0); }

    for (int c = 0; c < 8; ++c) {
        const short* Ard = Abuf + (c & 1) * (32 * LDA);
        short* Awr = Abuf + ((c + 1) & 1) * (32 * LDA);
        const float* gnext = gblock + (c + 1) * 25088;
        const bool stage = (c < 7);

        f32x4 acc00 = (f32x4)0.f, acc01 = (f32x4)0.f, acc10 = (f32x4)0.f, acc11 = (f32x4)0.f;
        bf16x8 bfE[2], bfO[2], afE[2], afO[2];
        f32x4 xE, xO;

        BF_ISSUE(0, bfE);
        AF_ISSUE(0, afE);

        // ---- barrier-free K-loop: 25 steps of BK=32 ----
        // in-step order: [A-write][frag prefetch s+1][A-issue][MFMA s]
        // (A loads issued AFTER the frag loads so no frag-wait force-retires
        //  a young HBM A-load; A-writes get the full 2-step slack.)
        #pragma unroll
        for (int s = 0; s < 25; ++s) {
            if (stage) {
                if ((s & 1) == 0 && s >= 2 && s <= 22) {
                    const int r = s / 2 - 1;
                    if (r & 1) { A_WRITE(r, xO); } else { A_WRITE(r, xE); }
                }
                if (s == 23) { A_WRITE(11, xO); }
                if (s == 24) { A_WRITE(12, xE); }
            }
            if (s < 24) {
                if ((s + 1) & 1) { BF_ISSUE(s + 1, bfO); AF_ISSUE(s + 1, afO); }
                else             { BF_ISSUE(s + 1, bfE); AF_ISSUE(s + 1, afE); }
            }
            if (stage) {
                if ((s & 1) == 0 && s <= 20) {
                    const int r = s / 2;
                    if (r & 1) { A_ISSUE(r, xO); } else { A_ISSUE(r, xE); }
                }
                if (s == 21) { A_ISSUE(11, xO); }
                if (s == 22) { A_ISSUE(12, xE); }
            }
            if (s & 1) { DO_MFMA(afO, bfO); } else { DO_MFMA(afE, bfE); }
        }
        __syncthreads();   // A(c+1) published; all frag reads of Ard retired

        // ---- epilogue: h1 = relu(acc + b1) ----
        #pragma unroll
        for (int j = 0; j < 4; ++j) {
            int r0 = lg * 4 + j, r1 = 16 + lg * 4 + j;
            h1[r0 * LDH + wave * 32 + l16]      = f2bf(fmaxf(acc00[j] + b1v0, 0.f));
            h1[r0 * LDH + wave * 32 + 16 + l16] = f2bf(fmaxf(acc01[j] + b1v1, 0.f));
            h1[r1 * LDH + wave * 32 + l16]      = f2bf(fmaxf(acc10[j] + b1v0, 0.f));
            h1[r1 * LDH + wave * 32 + 16 + l16] = f2bf(fmaxf(acc11[j] + b1v1, 0.f));
        }
        __syncthreads();

        // ---- GEMM2 + softmax (waves 0,1 handle 16 rows each) ----
        if (wave < 2) {
            f32x4 acc2 = (f32x4)0.f;
            const short* h1r = h1 + (wave * 16 + l16) * LDH + lg * 8;
            const short* w2r = w2t + l16 * 256 + lg * 8;
            #pragma unroll
            for (int kk = 0; kk < 8; kk++) {
                bf16x8 a2 = *(const bf16x8*)(h1r + kk * 32);
                bf16x8 b2f = *(const bf16x8*)(w2r + kk * 32);
                acc2 = __builtin_amdgcn_mfma_f32_16x16x32_bf16(a2, b2f, acc2, 0, 0, 0);
            }
            float pv[4], mx[4];
            #pragma unroll
            for (int j = 0; j < 4; j++) {
                pv[j] = (l16 < 10) ? (acc2[j] + b2v) * 10.f : -1e30f;
                mx[j] = pv[j];
            }
            #pragma unroll
            for (int off = 1; off < 16; off <<= 1)
                #pragma unroll
                for (int j = 0; j < 4; j++)
                    mx[j] = fmaxf(mx[j], __shfl_xor(mx[j], off));
            float ex[4], sm[4];
            #pragma unroll
            for (int j = 0; j < 4; j++) { ex[j] = __expf(pv[j] - mx[j]); sm[j] = ex[j]; }
            #pragma unroll
            for (int off = 1; off < 16; off <<= 1)
                #pragma unroll
                for (int j = 0; j < 4; j++)
                    sm[j] += __shfl_xor(sm[j], off);
            if (l16 < 10)
                #pragma unroll
                for (int j = 0; j < 4; j++)
                    probs[(wave * 16 + lg * 4 + j) * 10 + l16] = ex[j] / sm[j];
        }
        __syncthreads();

        // ---- pointer mix: 8 samples x 10 digits ----
        if (t < 80) {
            int s = t / 10, d = t - s * 10;
            int pid = pids[c * 8 + s];
            const float* p1t = ptabs + pid * 4;
            const float* p2t = ptabs + 16 + pid * 4;
            float d1 = 0.f, d2 = 0.f;
            #pragma unroll
            for (int p = 0; p < 4; p++) {
                float pr = probs[(s * 4 + p) * 10 + d];
                d1 += p1t[p] * pr;
                d2 += p2t[p] * pr;
            }
            dist1[s * 10 + d] = d1;
            dist2[s * 10 + d] = d2;
        }
        __syncthreads();

        // ---- conv (i+j==k symmetric) + log; waves 3..7 fall through to next chunk ----
        if (t < 152) {
            int s = t / 19, k = t - s * 19;
            int ilo = k > 9 ? k - 9 : 0;
            int ihi = k < 9 ? k : 9;
            float sum = 0.f;
            for (int i = ilo; i <= ihi; i++)
                sum += dist1[s * 10 + i] * dist2[s * 10 + (k - i)];
            out[((long)blk * 64 + c * 8 + s) * 19 + k] = __logf(sum + 1e-10f);
        }
        // no barrier needed: next chunk's K-loop touches only Abuf/global,
        // disjoint from probs/dist; chunk-end sync orders the next epilogue.
    }
    #undef A_ISSUE
    #undef A_WRITE
    #undef BF_ISSUE
    #undef AF_ISSUE
    #undef DO_MFMA
}

extern "C" void kernel_launch(void* const* d_in, const int* in_sizes, int n_in,
                              void* d_out, int out_size, void* d_ws, size_t ws_size,
                              hipStream_t stream)
{
    const float* grid   = (const float*)d_in[0];
    const float* onehot = (const float*)d_in[1];
    const float* W1  = (const float*)d_in[2];
    const float* b1  = (const float*)d_in[3];
    const float* W2  = (const float*)d_in[4];
    const float* b2  = (const float*)d_in[5];
    const float* Wp  = (const float*)d_in[6];
    const float* bp  = (const float*)d_in[7];
    const float* Wr1 = (const float*)d_in[8];
    const float* br1 = (const float*)d_in[9];
    const float* Wr2 = (const float*)d_in[10];
    const float* br2 = (const float*)d_in[11];
    float* out = (float*)d_out;

    short* w1t = (short*)d_ws;               // 256 x 800 bf16 = 409,600 B
    short* w2t = w1t + 256 * KP;             // 16 x 256 bf16  = 8,192 B
    float* ptabs = (float*)(w2t + 16 * 256); // 2 x 4 x 4 f32  = 128 B

    init_kernel<<<256, 256, 0, stream>>>(W1, W2, Wp, bp, Wr1, br1, Wr2, br2, w1t, w2t, ptabs);

    const int B = in_sizes[1] / 4;           // 16384
    const int nblk = (B * 4) / 256;          // 256 persistent blocks
    fused_kernel<<<nblk, 512, 0, stream>>>(grid, onehot, b1, b2, w1t, w2t, ptabs, out);
}

// Round 6
// 71.965 us; speedup vs baseline: 2.2328x; 2.2328x over previous
//
#include <hip/hip_runtime.h>
#include <hip/hip_bf16.h>

typedef __attribute__((ext_vector_type(8))) short bf16x8;
typedef __attribute__((ext_vector_type(4))) float f32x4;

__device__ __forceinline__ short f2bf(float f) {
    union { float f; unsigned u; } v; v.f = f;
    unsigned r = v.u + 0x7fffu + ((v.u >> 16) & 1u);
    return (short)(r >> 16);
}

#define KP   800            // w1t K padded 784 -> 800
#define LDA  136            // A LDS row stride in shorts (128+8; 272B, 16B-aligned, bank-even)
#define LDB  40             // B LDS row stride in shorts (32+8; bank-even)
#define AS   (64 * LDA)     // one A buffer (shorts)
#define BS   (256 * LDB)    // one B buffer (shorts)

#define WAITL  asm volatile("s_waitcnt lgkmcnt(0)" ::: "memory")
#define SBAR   __builtin_amdgcn_s_barrier()
#define SCHED0 __builtin_amdgcn_sched_barrier(0)

// ---------------- init: transpose/convert weights, pointer tables ----------------
__global__ void init_kernel(const float* __restrict__ W1, const float* __restrict__ W2,
                            const float* __restrict__ Wp, const float* __restrict__ bp,
                            const float* __restrict__ Wr1, const float* __restrict__ br1,
                            const float* __restrict__ Wr2, const float* __restrict__ br2,
                            short* __restrict__ w1t, short* __restrict__ w2t,
                            float* __restrict__ ptabs)
{
    int tid = blockIdx.x * blockDim.x + threadIdx.x;
    int stride = gridDim.x * blockDim.x;
    for (int i = tid; i < 784 * 256; i += stride) {      // coalesced W1 read, scattered 2B store
        int k = i >> 8, n = i & 255;
        w1t[n * KP + k] = f2bf(W1[i]);
    }
    for (int i = tid; i < 256 * 16; i += stride) {       // zero-pad k in [784,800)
        int n = i >> 4, k = 784 + (i & 15);
        w1t[n * KP + k] = 0;
    }
    for (int i = tid; i < 16 * 256; i += stride) {       // w2t[n][k] = W2[k][n], N padded to 16
        int n = i >> 8, k = i & 255;
        float v = (n < 10) ? W2[k * 10 + n] : 0.f;
        w2t[i] = f2bf(v);
    }
    if (blockIdx.x == 0 && threadIdx.x < 8) {            // pointer tables: 4 programs only
        int which = threadIdx.x >> 2, p = threadIdx.x & 3;
        const float* Wr = which ? Wr2 : Wr1;
        const float* br = which ? br2 : br1;
        float s[4];
        for (int q = 0; q < 4; q++) {
            float a = br[q];
            for (int j = 0; j < 16; j++) a += (Wp[p * 16 + j] + bp[j]) * Wr[j * 4 + q];
            s[q] = a;
        }
        float m = fmaxf(fmaxf(s[0], s[1]), fmaxf(s[2], s[3]));
        float e[4]; float tot = 0.f;
        for (int q = 0; q < 4; q++) { e[q] = __expf(s[q] - m); tot += e[q]; }
        for (int q = 0; q < 4; q++) ptabs[which * 16 + p * 4 + q] = e[q] / tot;
    }
}

// ---------------- fused main kernel ----------------
// 1024 blocks x 512 threads (8 waves, 2x4). Tile 64 rows x 256 cols.
// A staged per K-GROUP of 128 (per row: 4 back-to-back dwordx4 = 512 B contiguous),
// double-buffered [2][64][136]. B (w1t, L2): per group a BURST of 4 tiles (8 loads)
// issued BEFORE the A loads, so compiler-counted vmcnt waits on B never drain A
// (in-order retirement). B double-buffered [2][256][40] at substep cadence.
__global__ __launch_bounds__(512, 4) void fused_kernel(
    const float* __restrict__ g_in, const float* __restrict__ onehot,
    const float* __restrict__ b1g, const float* __restrict__ b2g,
    const short* __restrict__ w1t, const short* __restrict__ w2t,
    const float* __restrict__ ptabs, float* __restrict__ out)
{
    __shared__ __align__(16) char lds[79616];
    short* Abuf  = (short*)lds;                 // [2][64][136] bf16 = 34,816 B
    short* Bbuf  = (short*)(lds + 34816);       // [2][256][40] bf16 = 40,960 B (ends 75,776)
    short* h1    = (short*)lds;                 // overlay: [64][264] bf16 = 33,792 B
    float* probs = (float*)(lds + 75776);       // [64][10] f32 = 2,560 B
    float* dist1 = (float*)(lds + 78336);       // [16][10] f32 = 640 B
    float* dist2 = (float*)(lds + 78976);       // [16][10] f32 = 640 B

    const int t = threadIdx.x;
    const int lane = t & 63, wave = t >> 6;
    const int l16 = lane & 15, lg = lane >> 4;
    const int wr = wave >> 2, wc = wave & 3;
    const int blk = blockIdx.x;

    // A staging: 8 threads/row, 64 B contiguous each (4 dwordx4 back-to-back)
    const int arow = t >> 3, tr = t & 7;
    const float* gA = g_in + ((long)blk * 64 + arow) * 784 + tr * 16;
    // B staging: 2 threads/row, 16 shorts each
    const int bn = t >> 1, bh = t & 1;
    const short* gw1 = w1t + bn * KP + bh * 16;
    short* wBbase = Bbuf + bn * LDB + bh * 16;
    short* wAbase = Abuf + arow * LDA + tr * 16;

    f32x4 acc[2][4];
    #pragma unroll
    for (int mi = 0; mi < 2; mi++)
        #pragma unroll
        for (int ni = 0; ni < 4; ni++)
            acc[mi][ni] = (f32x4)0.f;

    // burst registers
    bf16x8 tB[4][2];                            // 4 B tiles x 16 shorts
    f32x4 xA0, xA1, xA2, xA3;                   // A: 16 floats

    auto ldBt = [&](int tile, int colbase) {
        const short* p = gw1 + colbase;
        tB[tile][0] = *(const bf16x8*)p;
        tB[tile][1] = *(const bf16x8*)(p + 8);
    };
    auto wrBt = [&](int tile, int buf) {
        short* w = wBbase + buf * BS;
        *(bf16x8*)w = tB[tile][0];
        *(bf16x8*)(w + 8) = tB[tile][1];
    };
    auto ldA = [&](int g1) {                    // load A tile g1 (cols g1*128 + tr*16 ..)
        const float* p = gA + g1 * 128;
        if ((g1 < 6) | (tr == 0)) {
            xA0 = *(const f32x4*)p;       xA1 = *(const f32x4*)(p + 4);
            xA2 = *(const f32x4*)(p + 8); xA3 = *(const f32x4*)(p + 12);
        } else { xA0 = (f32x4)0.f; xA1 = (f32x4)0.f; xA2 = (f32x4)0.f; xA3 = (f32x4)0.f; }
    };
    auto wrA = [&](int g1) {
        bf16x8 a0, a1;
        a0[0]=f2bf(xA0[0]); a0[1]=f2bf(xA0[1]); a0[2]=f2bf(xA0[2]); a0[3]=f2bf(xA0[3]);
        a0[4]=f2bf(xA1[0]); a0[5]=f2bf(xA1[1]); a0[6]=f2bf(xA1[2]); a0[7]=f2bf(xA1[3]);
        a1[0]=f2bf(xA2[0]); a1[1]=f2bf(xA2[1]); a1[2]=f2bf(xA2[2]); a1[3]=f2bf(xA2[3]);
        a1[4]=f2bf(xA3[0]); a1[5]=f2bf(xA3[1]); a1[6]=f2bf(xA3[2]); a1[7]=f2bf(xA3[3]);
        short* w = wAbase + (g1 & 1) * AS;
        *(bf16x8*)w = a0;
        *(bf16x8*)(w + 8) = a1;
    };
    auto mfmaSub = [&](int g, int s) {          // substep s of group g (s compile-time)
        const short* ab = Abuf + (g & 1) * AS;
        const short* bb = Bbuf + (s & 1) * BS;
        bf16x8 aF[2], bF[4];
        #pragma unroll
        for (int mi = 0; mi < 2; mi++)
            aF[mi] = *(const bf16x8*)(ab + (wr * 32 + mi * 16 + l16) * LDA + s * 32 + lg * 8);
        #pragma unroll
        for (int ni = 0; ni < 4; ni++)
            bF[ni] = *(const bf16x8*)(bb + (wc * 64 + ni * 16 + l16) * LDB + lg * 8);
        #pragma unroll
        for (int mi = 0; mi < 2; mi++)
            #pragma unroll
            for (int ni = 0; ni < 4; ni++)
                acc[mi][ni] = __builtin_amdgcn_mfma_f32_16x16x32_bf16(aF[mi], bF[ni], acc[mi][ni], 0, 0, 0);
    };

    // ---- prologue: T(0,0) -> buf0, A(0) -> Abuf[0] ----
    ldBt(0, 0); SCHED0;
    ldA(0); SCHED0;
    wrBt(0, 0);
    wrA(0);
    WAITL; SBAR; SCHED0;

    // ---- groups 0..5 (4 substeps each) ----
    for (int g = 0; g < 6; ++g) {
        const int cb = g * 128;
        // burst: B tiles (g,1),(g,2),(g,3),(g+1,0) FIRST (oldest), then A(g+1) (youngest)
        ldBt(0, cb + 32); ldBt(1, cb + 64); ldBt(2, cb + 96); ldBt(3, cb + 128); SCHED0;
        ldA(g + 1); SCHED0;

        // sub 0: write T(g,1)->buf1 (auto vmcnt wait drains only B0,B1)
        wrBt(0, 1);
        mfmaSub(g, 0);
        WAITL; SBAR; SCHED0;
        // sub 1: write T(g,2)->buf0
        wrBt(1, 0);
        mfmaSub(g, 1);
        WAITL; SBAR; SCHED0;
        // sub 2: write T(g,3)->buf1
        wrBt(2, 1);
        mfmaSub(g, 2);
        WAITL; SBAR; SCHED0;
        // sub 3: write T(g+1,0)->buf0 and A(g+1) (A drained here, ~3 substeps after issue)
        wrBt(3, 0);
        wrA(g + 1);
        mfmaSub(g, 3);
        WAITL; SBAR; SCHED0;
    }

    // ---- group 6: single substep (k = 768..799; cols 784..799 are zero-padded) ----
    mfmaSub(6, 0);
    WAITL; SBAR;                                 // all LDS reads retired -> safe to overlay

    // ---- epilogue 1: h1 = relu(acc + b1) ----
    #pragma unroll
    for (int mi = 0; mi < 2; mi++) {
        const int R = wr * 32 + mi * 16 + lg * 4;
        #pragma unroll
        for (int ni = 0; ni < 4; ni++) {
            const int N = wc * 64 + ni * 16 + l16;
            const float bias = b1g[N];
            #pragma unroll
            for (int j = 0; j < 4; j++) {
                float v = acc[mi][ni][j] + bias;
                h1[(R + j) * 264 + N] = f2bf(fmaxf(v, 0.f));
            }
        }
    }
    __syncthreads();

    // ---- GEMM2 (waves 0-3): logits = h1 @ W2 (+b2), wave w rows 16w..16w+15 ----
    if (wave < 4) {
        f32x4 acc2 = (f32x4)0.f;
        const short* h1r = h1 + (wave * 16 + l16) * 264 + lg * 8;
        const short* w2r = w2t + l16 * 256 + lg * 8;
        #pragma unroll
        for (int kk = 0; kk < 8; kk++) {
            bf16x8 a2 = *(const bf16x8*)(h1r + kk * 32);
            bf16x8 b2f = *(const bf16x8*)(w2r + kk * 32);
            acc2 = __builtin_amdgcn_mfma_f32_16x16x32_bf16(a2, b2f, acc2, 0, 0, 0);
        }
        // softmax(logits/0.1): C frag row = lg*4+j, col = l16
        const float b2v = (l16 < 10) ? b2g[l16] : 0.f;
        float pv[4], mx[4];
        #pragma unroll
        for (int j = 0; j < 4; j++) {
            pv[j] = (l16 < 10) ? (acc2[j] + b2v) * 10.f : -1e30f;
            mx[j] = pv[j];
        }
        #pragma unroll
        for (int off = 1; off < 16; off <<= 1)
            #pragma unroll
            for (int j = 0; j < 4; j++)
                mx[j] = fmaxf(mx[j], __shfl_xor(mx[j], off));
        float ex[4], sm[4];
        #pragma unroll
        for (int j = 0; j < 4; j++) { ex[j] = __expf(pv[j] - mx[j]); sm[j] = ex[j]; }
        #pragma unroll
        for (int off = 1; off < 16; off <<= 1)
            #pragma unroll
            for (int j = 0; j < 4; j++)
                sm[j] += __shfl_xor(sm[j], off);
        if (l16 < 10)
            #pragma unroll
            for (int j = 0; j < 4; j++)
                probs[(wave * 16 + lg * 4 + j) * 10 + l16] = ex[j] / sm[j];
    }
    __syncthreads();

    // ---- pointer mix: 16 samples x 10 digits ----
    if (t < 160) {
        int s = t / 10, d = t - s * 10;
        const float* oh = onehot + ((long)blk * 16 + s) * 4;
        int pid = (int)(oh[1] + 2.f * oh[2] + 3.f * oh[3] + 0.5f);
        const float* p1t = ptabs + pid * 4;
        const float* p2t = ptabs + 16 + pid * 4;
        float d1 = 0.f, d2 = 0.f;
        #pragma unroll
        for (int p = 0; p < 4; p++) {
            float pr = probs[(s * 4 + p) * 10 + d];
            d1 += p1t[p] * pr;
            d2 += p2t[p] * pr;
        }
        dist1[s * 10 + d] = d1;
        dist2[s * 10 + d] = d2;
    }
    __syncthreads();

    // ---- conv (i+j==k symmetric: symmetrization is a no-op) + log ----
    if (t < 304) {
        int s = t / 19, k = t - s * 19;
        int ilo = k > 9 ? k - 9 : 0;
        int ihi = k < 9 ? k : 9;
        float sum = 0.f;
        for (int i = ilo; i <= ihi; i++)
            sum += dist1[s * 10 + i] * dist2[s * 10 + (k - i)];
        out[((long)blk * 16 + s) * 19 + k] = __logf(sum + 1e-10f);
    }
}

extern "C" void kernel_launch(void* const* d_in, const int* in_sizes, int n_in,
                              void* d_out, int out_size, void* d_ws, size_t ws_size,
                              hipStream_t stream)
{
    const float* grid   = (const float*)d_in[0];
    const float* onehot = (const float*)d_in[1];
    const float* W1  = (const float*)d_in[2];
    const float* b1  = (const float*)d_in[3];
    const float* W2  = (const float*)d_in[4];
    const float* b2  = (const float*)d_in[5];
    const float* Wp  = (const float*)d_in[6];
    const float* bp  = (const float*)d_in[7];
    const float* Wr1 = (const float*)d_in[8];
    const float* br1 = (const float*)d_in[9];
    const float* Wr2 = (const float*)d_in[10];
    const float* br2 = (const float*)d_in[11];
    float* out = (float*)d_out;

    short* w1t = (short*)d_ws;               // 256 x 800 bf16 = 409,600 B
    short* w2t = w1t + 256 * KP;             // 16 x 256 bf16  = 8,192 B
    float* ptabs = (float*)(w2t + 16 * 256); // 2 x 4 x 4 f32  = 128 B

    init_kernel<<<256, 256, 0, stream>>>(W1, W2, Wp, bp, Wr1, br1, Wr2, br2, w1t, w2t, ptabs);

    const int B = in_sizes[1] / 4;           // 16384
    const int nblk = (B * 4) / 64;           // 1024
    fused_kernel<<<nblk, 512, 0, stream>>>(grid, onehot, b1, b2, w1t, w2t, ptabs, out);
}

// Round 7
// 56.200 us; speedup vs baseline: 2.8591x; 1.2805x over previous
//
#include <hip/hip_runtime.h>
#include <hip/hip_bf16.h>

typedef __attribute__((ext_vector_type(8))) short bf16x8;
typedef __attribute__((ext_vector_type(4))) float f32x4;

__device__ __forceinline__ short f2bf(float f) {
    union { float f; unsigned u; } v; v.f = f;
    unsigned r = v.u + 0x7fffu + ((v.u >> 16) & 1u);
    return (short)(r >> 16);
}

#define KP  800   // K padded 784 -> 800 (25 * 32)
#define LDK 40    // LDS row length in bf16 (32 + 8 pad)
#define NKT 25    // K-steps

// ---------------- init: LDS-tiled transpose (coalesced both sides) ----------------
// Blocks 0..199: 32x32 tile of W1 -> w1t.  Block 200: w2t + ptabs.
__global__ __launch_bounds__(256) void init_kernel(
    const float* __restrict__ W1, const float* __restrict__ W2,
    const float* __restrict__ Wp, const float* __restrict__ bp,
    const float* __restrict__ Wr1, const float* __restrict__ br1,
    const float* __restrict__ Wr2, const float* __restrict__ br2,
    short* __restrict__ w1t, short* __restrict__ w2t,
    float* __restrict__ ptabs)
{
    const int b = blockIdx.x;
    if (b < 200) {
        // tile (kt, nt): k in [kt*32, kt*32+32), n in [nt*32, nt*32+32)
        const int kt = b >> 3, nt = b & 7;
        __shared__ float tile[32][33];
        const int x = threadIdx.x & 31, y = threadIdx.x >> 5;
        // load: coalesced over n (x); 4 k-rows per thread
        #pragma unroll
        for (int r = 0; r < 4; ++r) {
            int kl = y + r * 8;
            int k = kt * 32 + kl, n = nt * 32 + x;
            tile[kl][x] = (k < 784) ? W1[k * 256 + n] : 0.f;
        }
        __syncthreads();
        // store: coalesced over k (x); 4 n-rows per thread
        #pragma unroll
        for (int r = 0; r < 4; ++r) {
            int nl = y + r * 8;
            int n = nt * 32 + nl, k = kt * 32 + x;
            w1t[n * KP + k] = f2bf(tile[x][nl]);
        }
    } else {
        // w2t[n][k] = W2[k][n], N padded to 16 (16*256 = 4096 elems, 16/thread)
        for (int i = threadIdx.x; i < 16 * 256; i += 256) {
            int n = i >> 8, k = i & 255;
            float v = (n < 10) ? W2[k * 10 + n] : 0.f;
            w2t[i] = f2bf(v);
        }
        if (threadIdx.x < 8) {                 // pointer tables: 4 programs only
            int which = threadIdx.x >> 2, p = threadIdx.x & 3;
            const float* Wr = which ? Wr2 : Wr1;
            const float* br = which ? br2 : br1;
            float s[4];
            for (int q = 0; q < 4; q++) {
                float a = br[q];
                for (int j = 0; j < 16; j++) a += (Wp[p * 16 + j] + bp[j]) * Wr[j * 4 + q];
                s[q] = a;
            }
            float m = fmaxf(fmaxf(s[0], s[1]), fmaxf(s[2], s[3]));
            float e[4]; float tot = 0.f;
            for (int q = 0; q < 4; q++) { e[q] = __expf(s[q] - m); tot += e[q]; }
            for (int q = 0; q < 4; q++) ptabs[which * 16 + p * 4 + q] = e[q] / tot;
        }
    }
}

// ---------------- fused main kernel (R2 structure, proven 55.9) ----------------
// 512 blocks x 512 threads (8 waves, 2x4 wave grid). Tile: 128 rows x 256 cols, BK=32.
__global__ __launch_bounds__(512, 4) void fused_kernel(
    const float* __restrict__ g_in, const float* __restrict__ onehot,
    const float* __restrict__ b1g, const float* __restrict__ b2g,
    const short* __restrict__ w1t, const short* __restrict__ w2t,
    const float* __restrict__ ptabs, float* __restrict__ out)
{
    __shared__ __align__(16) char lds[78464];
    short* Abuf = (short*)lds;                  // 2 x 128 x LDK bf16 = 20480 B
    short* Bbuf = (short*)(lds + 20480);        // 2 x 256 x LDK bf16 = 40960 B
    short* h1   = (short*)lds;                  // overlay: 128 x 264 bf16 = 67584 B
    float* probs = (float*)(lds + 67584);       // 128 x 16 f32 = 8192 B
    float* dist1 = (float*)(lds + 75776);       // 32 x 10 f32
    float* dist2 = (float*)(lds + 77056);       // 32 x 10 f32 (ends 78336)

    const int t = threadIdx.x;
    const int lane = t & 63, wave = t >> 6;
    const int l16 = lane & 15, lg = lane >> 4;
    const int wr = wave >> 2, wc = wave & 3;
    const int blk = blockIdx.x;

    // staging coords: A: thread -> (row, 8-float chunk); B: thread -> (n-row, 16-bf16 half)
    const int ar = t >> 2, aq = t & 3;
    const int bn = t >> 1, bh = t & 1;
    const float* gA = g_in + ((long)blk * 128 + ar) * 784 + aq * 8;
    const short* gB = w1t + bn * KP + bh * 16;
    short* awp = Abuf + ar * LDK + aq * 8;
    short* bwp = Bbuf + bn * LDK + bh * 16;

    f32x4 acc[4][4];
    #pragma unroll
    for (int mi = 0; mi < 4; mi++)
        #pragma unroll
        for (int ni = 0; ni < 4; ni++)
            acc[mi][ni] = (f32x4)0.f;

    f32x4 x0, x1; bf16x8 y0, y1;
    auto load_tile = [&](int kt) {
        const int k0 = kt * 32;
        if (k0 + aq * 8 < 784) {           // chunks are 8-aligned: fully valid or fully pad
            x0 = *(const f32x4*)(gA + k0);
            x1 = *(const f32x4*)(gA + k0 + 4);
        } else { x0 = (f32x4)0.f; x1 = (f32x4)0.f; }
        y0 = *(const bf16x8*)(gB + k0);
        y1 = *(const bf16x8*)(gB + k0 + 8);
    };
    auto write_tile = [&](int buf) {
        bf16x8 a8;
        a8[0] = f2bf(x0[0]); a8[1] = f2bf(x0[1]); a8[2] = f2bf(x0[2]); a8[3] = f2bf(x0[3]);
        a8[4] = f2bf(x1[0]); a8[5] = f2bf(x1[1]); a8[6] = f2bf(x1[2]); a8[7] = f2bf(x1[3]);
        *(bf16x8*)(awp + buf * (128 * LDK)) = a8;
        *(bf16x8*)(bwp + buf * (256 * LDK)) = y0;
        *(bf16x8*)(bwp + buf * (256 * LDK) + 8) = y1;
    };

    // ---- GEMM1: h1 = relu(grid @ W1 + b1), double-buffered ----
    load_tile(0); write_tile(0);
    __syncthreads();
    int cur = 0;
    for (int kt = 0; kt < NKT; kt++) {
        const bool more = (kt + 1 < NKT);
        if (more) load_tile(kt + 1);       // issue global loads early (latency under MFMA)
        const short* ab = Abuf + cur * (128 * LDK);
        const short* bb = Bbuf + cur * (256 * LDK);
        bf16x8 aF[4], bF[4];
        #pragma unroll
        for (int mi = 0; mi < 4; mi++)
            aF[mi] = *(const bf16x8*)(ab + (wr * 64 + mi * 16 + l16) * LDK + lg * 8);
        #pragma unroll
        for (int ni = 0; ni < 4; ni++)
            bF[ni] = *(const bf16x8*)(bb + (wc * 64 + ni * 16 + l16) * LDK + lg * 8);
        #pragma unroll
        for (int mi = 0; mi < 4; mi++)
            #pragma unroll
            for (int ni = 0; ni < 4; ni++)
                acc[mi][ni] = __builtin_amdgcn_mfma_f32_16x16x32_bf16(aF[mi], bF[ni], acc[mi][ni], 0, 0, 0);
        if (more) write_tile(cur ^ 1);
        __syncthreads();
        cur ^= 1;
    }

    // ---- epilogue 1: relu + bias -> h1 (bf16) in LDS (overlays gemm buffers) ----
    #pragma unroll
    for (int mi = 0; mi < 4; mi++) {
        const int R = wr * 64 + mi * 16 + lg * 4;
        #pragma unroll
        for (int ni = 0; ni < 4; ni++) {
            const int N = wc * 64 + ni * 16 + l16;
            const float bias = b1g[N];
            #pragma unroll
            for (int j = 0; j < 4; j++) {
                float v = acc[mi][ni][j] + bias;
                h1[(R + j) * 264 + N] = f2bf(fmaxf(v, 0.f));
            }
        }
    }
    __syncthreads();

    // ---- GEMM2: logits = h1 @ W2 (+b2), wave w owns rows 16w..16w+15, N=16 (10 valid) ----
    f32x4 acc2 = (f32x4)0.f;
    const short* h1r = h1 + (wave * 16 + l16) * 264 + lg * 8;
    const short* w2r = w2t + l16 * 256 + lg * 8;
    #pragma unroll
    for (int kk = 0; kk < 8; kk++) {
        bf16x8 a2 = *(const bf16x8*)(h1r + kk * 32);
        bf16x8 b2f = *(const bf16x8*)(w2r + kk * 32);
        acc2 = __builtin_amdgcn_mfma_f32_16x16x32_bf16(a2, b2f, acc2, 0, 0, 0);
    }

    // ---- softmax(logits / 0.1) per row; C frag: row = lg*4+j, col = l16 ----
    const float b2v = (l16 < 10) ? b2g[l16] : 0.f;
    float pv[4], mx[4];
    #pragma unroll
    for (int j = 0; j < 4; j++) {
        pv[j] = (l16 < 10) ? (acc2[j] + b2v) * 10.f : -1e30f;
        mx[j] = pv[j];
    }
    #pragma unroll
    for (int off = 1; off < 16; off <<= 1)
        #pragma unroll
        for (int j = 0; j < 4; j++)
            mx[j] = fmaxf(mx[j], __shfl_xor(mx[j], off));
    float ex[4], sm[4];
    #pragma unroll
    for (int j = 0; j < 4; j++) { ex[j] = __expf(pv[j] - mx[j]); sm[j] = ex[j]; }
    #pragma unroll
    for (int off = 1; off < 16; off <<= 1)
        #pragma unroll
        for (int j = 0; j < 4; j++)
            sm[j] += __shfl_xor(sm[j], off);
    #pragma unroll
    for (int j = 0; j < 4; j++)
        probs[(wave * 16 + lg * 4 + j) * 16 + l16] = ex[j] / sm[j];
    __syncthreads();

    // ---- pointer mix: dist1/dist2 (32 samples x 10 digits) ----
    if (t < 320) {
        int s = t / 10, d = t - s * 10;
        const float* oh = onehot + ((long)blk * 32 + s) * 4;
        int pid = (int)(oh[1] + 2.f * oh[2] + 3.f * oh[3] + 0.5f);
        const float* p1t = ptabs + pid * 4;
        const float* p2t = ptabs + 16 + pid * 4;
        float d1 = 0.f, d2 = 0.f;
        #pragma unroll
        for (int p = 0; p < 4; p++) {
            float pr = probs[(s * 4 + p) * 16 + d];
            d1 += p1t[p] * pr;
            d2 += p2t[p] * pr;
        }
        dist1[s * 10 + d] = d1;
        dist2[s * 10 + d] = d2;
    }
    __syncthreads();

    // ---- conv (i+j==k symmetric: symmetrization is a no-op) + log ----
    for (int idx = t; idx < 608; idx += 512) {
        int s = idx / 19, k = idx - s * 19;
        int ilo = k > 9 ? k - 9 : 0;
        int ihi = k < 9 ? k : 9;
        float sum = 0.f;
        for (int i = ilo; i <= ihi; i++)
            sum += dist1[s * 10 + i] * dist2[s * 10 + (k - i)];
        out[((long)blk * 32 + s) * 19 + k] = __logf(sum + 1e-10f);
    }
}

extern "C" void kernel_launch(void* const* d_in, const int* in_sizes, int n_in,
                              void* d_out, int out_size, void* d_ws, size_t ws_size,
                              hipStream_t stream)
{
    const float* grid   = (const float*)d_in[0];
    const float* onehot = (const float*)d_in[1];
    const float* W1  = (const float*)d_in[2];
    const float* b1  = (const float*)d_in[3];
    const float* W2  = (const float*)d_in[4];
    const float* b2  = (const float*)d_in[5];
    const float* Wp  = (const float*)d_in[6];
    const float* bp  = (const float*)d_in[7];
    const float* Wr1 = (const float*)d_in[8];
    const float* br1 = (const float*)d_in[9];
    const float* Wr2 = (const float*)d_in[10];
    const float* br2 = (const float*)d_in[11];
    float* out = (float*)d_out;

    short* w1t = (short*)d_ws;              // 256 x 800 bf16 = 409600 B
    short* w2t = w1t + 256 * KP;            // 16 x 256 bf16  = 8192 B
    float* ptabs = (float*)(w2t + 16 * 256);// 2 x 4 x 4 f32  = 128 B

    init_kernel<<<201, 256, 0, stream>>>(W1, W2, Wp, bp, Wr1, br1, Wr2, br2, w1t, w2t, ptabs);

    const int B = in_sizes[1] / 4;          // 16384
    const int nblk = (B * 4) / 128;         // 512
    fused_kernel<<<nblk, 512, 0, stream>>>(grid, onehot, b1, b2, w1t, w2t, ptabs, out);
}

// Round 8
// 56.015 us; speedup vs baseline: 2.8686x; 1.0033x over previous
//
#include <hip/hip_runtime.h>
#include <hip/hip_bf16.h>

typedef __attribute__((ext_vector_type(8))) short bf16x8;
typedef __attribute__((ext_vector_type(4))) float f32x4;

__device__ __forceinline__ short f2bf(float f) {
    union { float f; unsigned u; } v; v.f = f;
    unsigned r = v.u + 0x7fffu + ((v.u >> 16) & 1u);
    return (short)(r >> 16);
}

__device__ __forceinline__ void gl2lds16(const void* g, void* l) {
    __builtin_amdgcn_global_load_lds(
        (const __attribute__((address_space(1))) unsigned int*)g,
        (__attribute__((address_space(3))) unsigned int*)l,
        16, 0, 0);
}

#define KP  800   // K padded 784 -> 800 (25 * 32)
#define LDK 40    // A LDS row length in bf16 (32 + 8 pad)
#define ABS (128 * LDK)       // one A buffer (shorts)
#define BBS (256 * 32)        // one B buffer (shorts), linear for gl_lds
#define BBSB 16384            // one B buffer (bytes)

#define WAITV2 asm volatile("s_waitcnt vmcnt(2)" ::: "memory")
#define WAITV0 asm volatile("s_waitcnt vmcnt(0)" ::: "memory")
#define WAITL  asm volatile("s_waitcnt lgkmcnt(0)" ::: "memory")
#define SBAR   __builtin_amdgcn_s_barrier()
#define SCHED0 __builtin_amdgcn_sched_barrier(0)

// ---------------- init: LDS-tiled transpose (coalesced both sides) ----------------
__global__ __launch_bounds__(256) void init_kernel(
    const float* __restrict__ W1, const float* __restrict__ W2,
    const float* __restrict__ Wp, const float* __restrict__ bp,
    const float* __restrict__ Wr1, const float* __restrict__ br1,
    const float* __restrict__ Wr2, const float* __restrict__ br2,
    short* __restrict__ w1t, short* __restrict__ w2t,
    float* __restrict__ ptabs)
{
    const int b = blockIdx.x;
    if (b < 200) {
        const int kt = b >> 3, nt = b & 7;
        __shared__ float tile[32][33];
        const int x = threadIdx.x & 31, y = threadIdx.x >> 5;
        #pragma unroll
        for (int r = 0; r < 4; ++r) {
            int kl = y + r * 8;
            int k = kt * 32 + kl, n = nt * 32 + x;
            tile[kl][x] = (k < 784) ? W1[k * 256 + n] : 0.f;
        }
        __syncthreads();
        #pragma unroll
        for (int r = 0; r < 4; ++r) {
            int nl = y + r * 8;
            int n = nt * 32 + nl, k = kt * 32 + x;
            w1t[n * KP + k] = f2bf(tile[x][nl]);
        }
    } else {
        for (int i = threadIdx.x; i < 16 * 256; i += 256) {
            int n = i >> 8, k = i & 255;
            float v = (n < 10) ? W2[k * 10 + n] : 0.f;
            w2t[i] = f2bf(v);
        }
        if (threadIdx.x < 8) {
            int which = threadIdx.x >> 2, p = threadIdx.x & 3;
            const float* Wr = which ? Wr2 : Wr1;
            const float* br = which ? br2 : br1;
            float s[4];
            for (int q = 0; q < 4; q++) {
                float a = br[q];
                for (int j = 0; j < 16; j++) a += (Wp[p * 16 + j] + bp[j]) * Wr[j * 4 + q];
                s[q] = a;
            }
            float m = fmaxf(fmaxf(s[0], s[1]), fmaxf(s[2], s[3]));
            float e[4]; float tot = 0.f;
            for (int q = 0; q < 4; q++) { e[q] = __expf(s[q] - m); tot += e[q]; }
            for (int q = 0; q < 4; q++) ptabs[which * 16 + p * 4 + q] = e[q] / tot;
        }
    }
}

// ---------------- fused main kernel ----------------
// R2 shell; K-steps in PAIRS: both steps' A-loads issued back-to-back at the even
// step so each grid row's 256 B arrive as one DRAM burst. B via global_load_lds,
// triple-buffered [3][256][32] linear, 16-B-slot XOR source-pre-swizzle.
__global__ __launch_bounds__(512, 4) void fused_kernel(
    const float* __restrict__ g_in, const float* __restrict__ onehot,
    const float* __restrict__ b1g, const float* __restrict__ b2g,
    const short* __restrict__ w1t, const short* __restrict__ w2t,
    const float* __restrict__ ptabs, float* __restrict__ out)
{
    __shared__ __align__(16) char lds[78336];
    short* Abuf = (short*)lds;                  // [2][128][40] bf16 = 20,480 B
    short* Bbuf = (short*)(lds + 20480);        // [3][256][32] bf16 = 49,152 B (ends 69,632)
    short* h1   = (short*)lds;                  // overlay: [128][264] bf16 = 67,584 B
    float* dist1 = (float*)(lds + 67584);       // [32][10] f32 = 1,280 B
    float* dist2 = (float*)(lds + 68864);       // [32][10] f32 = 1,280 B
    float* probs = (float*)(lds + 70144);       // [128][16] f32 = 8,192 B (ends 78,336)

    const int t = threadIdx.x;
    const int lane = t & 63, wave = t >> 6;
    const int l16 = lane & 15, lg = lane >> 4;
    const int wr = wave >> 2, wc = wave & 3;
    const int blk = blockIdx.x;

    // A staging: thread -> (row ar, 8-float chunk aq)
    const int ar = t >> 2, aq = t & 3;
    const float* gA = g_in + ((long)blk * 128 + ar) * 784 + aq * 8;
    short* awp = Abuf + ar * LDK + aq * 8;
    // B staging via gl_lds: thread covers w1t row t>>2 (and +128), 16-B slot (t&3),
    // source chunk XOR-swizzled by (row&3) so frag reads spread banks.
    const int brow = t >> 2;
    const short* gBsw = w1t + brow * KP + ((aq ^ (brow & 3)) * 8);
    char* ldsB = (char*)Bbuf;
    const int bswz = lg ^ (l16 & 3);            // frag-read slot swizzle

    f32x4 acc[4][4];
    #pragma unroll
    for (int mi = 0; mi < 4; mi++)
        #pragma unroll
        for (int ni = 0; ni < 4; ni++)
            acc[mi][ni] = (f32x4)0.f;

    f32x4 xa0, xa1, xb0, xb1;                   // two named A staging sets

    auto issueB = [&](int s) {                  // B tile s -> buf s%3 (2 gl_lds)
        const short* g0 = gBsw + s * 32;
        char* l0 = ldsB + (s % 3) * BBSB + wave * 1024;
        gl2lds16(g0, l0);
        gl2lds16(g0 + 128 * KP, l0 + 8192);
    };
    auto issueA = [&](int kt, f32x4& x0, f32x4& x1) {
        const int k0 = kt * 32;
        if (k0 + aq * 8 < 784) {
            x0 = *(const f32x4*)(gA + k0);
            x1 = *(const f32x4*)(gA + k0 + 4);
        } else { x0 = (f32x4)0.f; x1 = (f32x4)0.f; }
    };
    auto writeA = [&](const f32x4& x0, const f32x4& x1, int buf) {
        bf16x8 a8;
        a8[0] = f2bf(x0[0]); a8[1] = f2bf(x0[1]); a8[2] = f2bf(x0[2]); a8[3] = f2bf(x0[3]);
        a8[4] = f2bf(x1[0]); a8[5] = f2bf(x1[1]); a8[6] = f2bf(x1[2]); a8[7] = f2bf(x1[3]);
        *(bf16x8*)(awp + buf * ABS) = a8;
    };
    auto mfmaStep = [&](int abuf, int bbuf) {
        const short* ab = Abuf + abuf * ABS;
        const short* bb = Bbuf + bbuf * BBS;
        bf16x8 aF[4], bF[4];
        #pragma unroll
        for (int mi = 0; mi < 4; mi++)
            aF[mi] = *(const bf16x8*)(ab + (wr * 64 + mi * 16 + l16) * LDK + lg * 8);
        #pragma unroll
        for (int ni = 0; ni < 4; ni++)
            bF[ni] = *(const bf16x8*)(bb + (wc * 64 + ni * 16 + l16) * 32 + bswz * 8);
        #pragma unroll
        for (int mi = 0; mi < 4; mi++)
            #pragma unroll
            for (int ni = 0; ni < 4; ni++)
                acc[mi][ni] = __builtin_amdgcn_mfma_f32_16x16x32_bf16(aF[mi], bF[ni], acc[mi][ni], 0, 0, 0);
    };

    // ---- prologue: B(0)->buf0, A(0)->regs, publish ----
    issueB(0); SCHED0;
    issueA(0, xa0, xa1); SCHED0;
    writeA(xa0, xa1, 0);
    WAITV0; WAITL; SBAR;

    // ---- 12 step-pairs; even step issues the whole pair's loads back-to-back ----
    for (int g = 0; g < 12; ++g) {
        const int kt = 2 * g;
        // B tiles kt+1, kt+2 (oldest), then A sets kt+1, kt+2 (one 256-B burst/row)
        issueB(kt + 1); issueB(kt + 2); SCHED0;
        issueA(kt + 1, xa0, xa1); issueA(kt + 2, xb0, xb1); SCHED0;
        // even step kt: read A buf0, B buf kt%3
        mfmaStep(0, kt % 3);
        writeA(xa0, xa1, 1);                    // auto-wait drains B x4 + A1
        WAITV2; WAITL; SBAR; SCHED0;            // A2 (2 loads) stays in flight
        // odd step kt+1: read A buf1, B buf (kt+1)%3
        mfmaStep(1, (kt + 1) % 3);
        writeA(xb0, xb1, 0);
        WAITV0; WAITL; SBAR; SCHED0;
    }
    // ---- step 24 ----
    mfmaStep(0, 0);
    WAITL; SBAR;                                // all staging reads retired -> overlay safe

    // ---- epilogue 1: h1 = relu(acc + b1) (bf16, overlays staging) ----
    #pragma unroll
    for (int mi = 0; mi < 4; mi++) {
        const int R = wr * 64 + mi * 16 + lg * 4;
        #pragma unroll
        for (int ni = 0; ni < 4; ni++) {
            const int N = wc * 64 + ni * 16 + l16;
            const float bias = b1g[N];
            #pragma unroll
            for (int j = 0; j < 4; j++) {
                float v = acc[mi][ni][j] + bias;
                h1[(R + j) * 264 + N] = f2bf(fmaxf(v, 0.f));
            }
        }
    }
    __syncthreads();

    // ---- GEMM2: logits = h1 @ W2 (+b2), wave w owns rows 16w..16w+15 ----
    f32x4 acc2 = (f32x4)0.f;
    const short* h1r = h1 + (wave * 16 + l16) * 264 + lg * 8;
    const short* w2r = w2t + l16 * 256 + lg * 8;
    #pragma unroll
    for (int kk = 0; kk < 8; kk++) {
        bf16x8 a2 = *(const bf16x8*)(h1r + kk * 32);
        bf16x8 b2f = *(const bf16x8*)(w2r + kk * 32);
        acc2 = __builtin_amdgcn_mfma_f32_16x16x32_bf16(a2, b2f, acc2, 0, 0, 0);
    }

    // ---- softmax(logits / 0.1): C frag row = lg*4+j, col = l16 ----
    const float b2v = (l16 < 10) ? b2g[l16] : 0.f;
    float pv[4], mx[4];
    #pragma unroll
    for (int j = 0; j < 4; j++) {
        pv[j] = (l16 < 10) ? (acc2[j] + b2v) * 10.f : -1e30f;
        mx[j] = pv[j];
    }
    #pragma unroll
    for (int off = 1; off < 16; off <<= 1)
        #pragma unroll
        for (int j = 0; j < 4; j++)
            mx[j] = fmaxf(mx[j], __shfl_xor(mx[j], off));
    float ex[4], sm[4];
    #pragma unroll
    for (int j = 0; j < 4; j++) { ex[j] = __expf(pv[j] - mx[j]); sm[j] = ex[j]; }
    #pragma unroll
    for (int off = 1; off < 16; off <<= 1)
        #pragma unroll
        for (int j = 0; j < 4; j++)
            sm[j] += __shfl_xor(sm[j], off);
    #pragma unroll
    for (int j = 0; j < 4; j++)
        probs[(wave * 16 + lg * 4 + j) * 16 + l16] = ex[j] / sm[j];
    __syncthreads();

    // ---- pointer mix: dist1/dist2 (32 samples x 10 digits) ----
    if (t < 320) {
        int s = t / 10, d = t - s * 10;
        const float* oh = onehot + ((long)blk * 32 + s) * 4;
        int pid = (int)(oh[1] + 2.f * oh[2] + 3.f * oh[3] + 0.5f);
        const float* p1t = ptabs + pid * 4;
        const float* p2t = ptabs + 16 + pid * 4;
        float d1 = 0.f, d2 = 0.f;
        #pragma unroll
        for (int p = 0; p < 4; p++) {
            float pr = probs[(s * 4 + p) * 16 + d];
            d1 += p1t[p] * pr;
            d2 += p2t[p] * pr;
        }
        dist1[s * 10 + d] = d1;
        dist2[s * 10 + d] = d2;
    }
    __syncthreads();

    // ---- conv (i+j==k symmetric: symmetrization is a no-op) + log ----
    for (int idx = t; idx < 608; idx += 512) {
        int s = idx / 19, k = idx - s * 19;
        int ilo = k > 9 ? k - 9 : 0;
        int ihi = k < 9 ? k : 9;
        float sum = 0.f;
        for (int i = ilo; i <= ihi; i++)
            sum += dist1[s * 10 + i] * dist2[s * 10 + (k - i)];
        out[((long)blk * 32 + s) * 19 + k] = __logf(sum + 1e-10f);
    }
}

extern "C" void kernel_launch(void* const* d_in, const int* in_sizes, int n_in,
                              void* d_out, int out_size, void* d_ws, size_t ws_size,
                              hipStream_t stream)
{
    const float* grid   = (const float*)d_in[0];
    const float* onehot = (const float*)d_in[1];
    const float* W1  = (const float*)d_in[2];
    const float* b1  = (const float*)d_in[3];
    const float* W2  = (const float*)d_in[4];
    const float* b2  = (const float*)d_in[5];
    const float* Wp  = (const float*)d_in[6];
    const float* bp  = (const float*)d_in[7];
    const float* Wr1 = (const float*)d_in[8];
    const float* br1 = (const float*)d_in[9];
    const float* Wr2 = (const float*)d_in[10];
    const float* br2 = (const float*)d_in[11];
    float* out = (float*)d_out;

    short* w1t = (short*)d_ws;              // 256 x 800 bf16 = 409,600 B
    short* w2t = w1t + 256 * KP;            // 16 x 256 bf16  = 8,192 B
    float* ptabs = (float*)(w2t + 16 * 256);// 2 x 4 x 4 f32  = 128 B

    init_kernel<<<201, 256, 0, stream>>>(W1, W2, Wp, bp, Wr1, br1, Wr2, br2, w1t, w2t, ptabs);

    const int B = in_sizes[1] / 4;          // 16384
    const int nblk = (B * 4) / 128;         // 512
    fused_kernel<<<nblk, 512, 0, stream>>>(grid, onehot, b1, b2, w1t, w2t, ptabs, out);
}